// Round 8
// baseline (528.965 us; speedup 1.0000x reference)
//
#include <hip/hip_runtime.h>

#define B_ 2
#define S_ 2048
#define D_ 1024      // D_IN = DKQ = DV = E
#define H_ 16
#define HD_ 64       // DV / H

typedef _Float16 f16;
typedef _Float16 half8 __attribute__((ext_vector_type(8)));
typedef float float4_ __attribute__((ext_vector_type(4)));

#define N_W  (D_*D_)      // 1048576
#define N_MIX (H_*D_)     // 16384

// mixing scale: (1/sqrt(64)) * (1/ln2) -> softmax exp becomes bare exp2
#define MIX_SCALE 0.18033688011112042f

__device__ __forceinline__ void gl_lds16(const f16* g, const f16* l) {
  __builtin_amdgcn_global_load_lds(
      (const __attribute__((address_space(1))) void*)g,
      (__attribute__((address_space(3))) void*)l, 16, 0, 0);
}

__device__ __forceinline__ half8 cvt8(const float* p) {
  float4 a0 = *(const float4*)p, a1 = *(const float4*)(p+4);
  half8 h;
  h[0]=(f16)a0.x; h[1]=(f16)a0.y; h[2]=(f16)a0.z; h[3]=(f16)a0.w;
  h[4]=(f16)a1.x; h[5]=(f16)a1.y; h[6]=(f16)a1.z; h[7]=(f16)a1.w;
  return h;
}

// ---------------- QKV GEMM (fp32 in, fp16 MFMA, inline convert) ----------------
// z==2 (V) adds bias and writes TRANSPOSED: vT[b][ch][t]
// block (z=0,mt=0,nt=0) also converts mix -> mix16 (scaled).
#define BM 128
#define BN 128
#define BK 64
#define LDA 72   // BK + 8 pad

__global__ __launch_bounds__(256, 2) void qkv_kernel(
    const float* __restrict__ hs, const float* __restrict__ Wq,
    const float* __restrict__ Wk, const float* __restrict__ Wv,
    const float* __restrict__ bv, const float* __restrict__ mix,
    f16* __restrict__ q16, f16* __restrict__ k16, f16* __restrict__ vT,
    f16* __restrict__ mix16)
{
  const int z = blockIdx.z;
  const float* W = (z==0) ? Wq : (z==1) ? Wk : Wv;
  f16* out = (z==0) ? q16 : k16;
  const int mt = blockIdx.y, nt = blockIdx.x;
  const int tid = threadIdx.x;
  const int lane = tid & 63, wid = tid >> 6;
  const int wm = wid >> 1, wn = wid & 1;
  const int quad = lane >> 4, l16 = lane & 15;

  // designated block converts mix (16K elems) with scale folded
  if (z == 0 && mt == 0 && nt == 0) {
#pragma unroll
    for (int i = 0; i < 8; i++) {
      int e = (i*256 + tid) * 8;
      float4 a0 = *(const float4*)&mix[e], a1 = *(const float4*)&mix[e+4];
      half8 h;
      h[0]=(f16)(a0.x*MIX_SCALE); h[1]=(f16)(a0.y*MIX_SCALE);
      h[2]=(f16)(a0.z*MIX_SCALE); h[3]=(f16)(a0.w*MIX_SCALE);
      h[4]=(f16)(a1.x*MIX_SCALE); h[5]=(f16)(a1.y*MIX_SCALE);
      h[6]=(f16)(a1.z*MIX_SCALE); h[7]=(f16)(a1.w*MIX_SCALE);
      *(half8*)&mix16[e] = h;
    }
  }

  __shared__ __align__(16) f16 As[BM][LDA];
  __shared__ __align__(16) f16 Bs[BN][LDA];

  float4_ acc[4][4];
#pragma unroll
  for (int i=0;i<4;i++)
#pragma unroll
    for (int j=0;j<4;j++) acc[i][j] = (float4_)0.0f;

  const int row0 = mt*BM;
  const int col0 = nt*BN;

  for (int ko = 0; ko < D_; ko += BK) {
#pragma unroll
    for (int it=0; it<4; it++) {
      int c = it*256 + tid;
      int r = c >> 3, c8 = (c & 7)*8;
      *(half8*)&As[r][c8] = cvt8(&hs[(size_t)(row0+r)*D_ + ko + c8]);
      *(half8*)&Bs[r][c8] = cvt8(&W[(size_t)(col0+r)*D_ + ko + c8]);
    }
    __syncthreads();
#pragma unroll
    for (int kk=0; kk<BK; kk+=32) {
      half8 a[4], b[4];
#pragma unroll
      for (int i=0;i<4;i++) a[i] = *(const half8*)&As[wm*64+i*16+l16][kk+quad*8];
#pragma unroll
      for (int j=0;j<4;j++) b[j] = *(const half8*)&Bs[wn*64+j*16+l16][kk+quad*8];
#pragma unroll
      for (int i=0;i<4;i++)
#pragma unroll
        for (int j=0;j<4;j++)
          acc[i][j] = __builtin_amdgcn_mfma_f32_16x16x32_f16(a[i], b[j], acc[i][j], 0,0,0);
    }
    __syncthreads();
  }
#pragma unroll
  for (int i=0;i<4;i++) {
#pragma unroll
    for (int j=0;j<4;j++) {
      int colg = col0 + wn*64 + j*16 + l16;
      float bias = (z==2) ? bv[colg] : 0.0f;
#pragma unroll
      for (int r=0;r<4;r++) {
        int rowg = row0 + wm*64 + i*16 + quad*4 + r;
        f16 val = (f16)(acc[i][j][r] + bias);
        if (z == 2) {
          int bb = rowg >> 11, ss = rowg & (S_-1);
          vT[((size_t)bb*D_ + colg)*S_ + ss] = val;
        } else {
          out[(size_t)rowg*D_ + colg] = val;
        }
      }
    }
  }
}

// ---------------- flash attention (R6 structure): const-shift-free softmax, ----------------
// 2 k-tiles per q-stage, per-lane l partials, single epilogue reduction.
#define TQ 128
#define TK 128
#define LDP 136

__global__ __launch_bounds__(256, 2) void attn_kernel(
    const f16* __restrict__ q16, const f16* __restrict__ k16,
    const f16* __restrict__ vT, const f16* __restrict__ mix16,
    float* __restrict__ out)
{
  const int b = blockIdx.z;
  const int h = blockIdx.y;
  const int s0 = blockIdx.x * TQ;
  const int tid = threadIdx.x;
  const int lane = tid & 63, wid = tid >> 6;
  const int wm = wid >> 1, wn = wid & 1;
  const int quad = lane >> 4, l16 = lane & 15;

  // q padded (VALU, mix fused) + two k tiles (DMA, xor-swizzled); P aliases all
  __shared__ __align__(16) union {
    struct { f16 q[TQ][LDA]; f16 k0[TK*BK]; f16 k1[TK*BK]; } s1;  // 51200 B
    f16 P[TQ][LDP];                                               // 34816 B
  } u;
  __shared__ __align__(16) f16 mixrow[D_];   // 2 KB
  __shared__ __align__(16) float red_l[2][TQ];

  // per-lane l partials: 16 rows/lane (row = wm*64+i*16+quad*4+r)
  float l_lane[16];
#pragma unroll
  for (int t=0;t<16;t++) l_lane[t] = 0.0f;

  float4_ o_acc[4][2];
#pragma unroll
  for (int i=0;i<4;i++)
#pragma unroll
    for (int j=0;j<2;j++) o_acc[i][j] = (float4_)0.0f;

  const f16* qbase = q16 + (size_t)(b*S_ + s0)*D_;
  const f16* kbase = k16 + (size_t)b*S_*D_;
  const f16* vTb   = vT + (size_t)(b*D_ + h*HD_)*S_;

  // mix row -> LDS once (broadcast reads thereafter)
  if (tid < D_/8) *(half8*)&mixrow[tid*8] = *(const half8*)&mix16[h*D_ + tid*8];
  __syncthreads();

  for (int t0 = 0; t0 < S_; t0 += 2*TK) {
    // ---- S[2 tiles] = (q*mix) @ k^T over K=1024 ----
    float4_ sacc[2][4][4];
#pragma unroll
    for (int tt=0;tt<2;tt++)
#pragma unroll
      for (int i=0;i<4;i++)
#pragma unroll
        for (int j=0;j<4;j++) sacc[tt][i][j] = (float4_)0.0f;

    for (int ko = 0; ko < D_; ko += BK) {
      const f16* k0g = kbase + (size_t)t0*D_ + ko;
      const f16* k1g = k0g + (size_t)TK*D_;
#pragma unroll
      for (int c=0; c<4; c++) {
        int slot = (wid*4+c)*64 + lane;
        int r = slot >> 3;
        int gc = (slot & 7) ^ (r & 7);
        gl_lds16(k0g + (size_t)r*D_ + gc*8, u.s1.k0 + (size_t)(wid*4+c)*64*8);
        gl_lds16(k1g + (size_t)r*D_ + gc*8, u.s1.k1 + (size_t)(wid*4+c)*64*8);
      }
      // q-tile: VALU staging with mix fused (mix from LDS), once per 2 k-tiles
#pragma unroll
      for (int it=0; it<4; it++) {
        int c = it*256 + tid;
        int r = c >> 3, c8 = (c & 7)*8;
        half8 qv = *(const half8*)&qbase[(size_t)r*D_ + ko + c8];
        half8 mv = *(const half8*)&mixrow[ko + c8];
        *(half8*)&u.s1.q[r][c8] = qv * mv;
      }
      __syncthreads();
#pragma unroll
      for (int kk=0; kk<BK; kk+=32) {
        half8 a[4];
#pragma unroll
        for (int i=0;i<4;i++) a[i] = *(const half8*)&u.s1.q[wm*64+i*16+l16][kk+quad*8];
#pragma unroll
        for (int tt=0;tt<2;tt++) {
          const f16* kb = tt ? u.s1.k1 : u.s1.k0;
          half8 bf[4];
#pragma unroll
          for (int j=0;j<4;j++) {
            int rr = wn*64 + j*16 + l16;
            int ck = (kk >> 3) + quad;
            bf[j] = *(const half8*)&kb[(size_t)(((rr<<3) | (ck ^ (rr&7))) << 3)];
          }
#pragma unroll
          for (int i=0;i<4;i++)
#pragma unroll
            for (int j=0;j<4;j++)
              sacc[tt][i][j] = __builtin_amdgcn_mfma_f32_16x16x32_f16(a[i], bf[j], sacc[tt][i][j], 0,0,0);
        }
      }
      __syncthreads();
    }

    // ---- per sub-tile: P = exp2(S), l partials, P->LDS, PV ----
#pragma unroll
    for (int tt=0;tt<2;tt++) {
      // prefetch PV B-fragments first (global latency overlaps exp VALU)
      half8 vb[8];
#pragma unroll
      for (int ki=0; ki<4; ki++)
#pragma unroll
        for (int j=0; j<2; j++) {
          int ch = wn*32 + j*16 + l16;
          vb[ki*2+j] = *(const half8*)&vTb[(size_t)ch*S_ + t0 + tt*TK + ki*32 + quad*8];
        }

#pragma unroll
      for (int i=0;i<4;i++)
#pragma unroll
        for (int j=0;j<4;j++)
#pragma unroll
          for (int r=0;r<4;r++) {
            float p = __builtin_exp2f(sacc[tt][i][j][r]);
            l_lane[i*4+r] += p;
            u.P[wm*64+i*16+quad*4+r][wn*64+j*16+l16] = (f16)p;
          }

      __syncthreads();

#pragma unroll
      for (int ki=0; ki<4; ki++) {
        half8 pa[4];
#pragma unroll
        for (int i=0;i<4;i++) pa[i] = *(const half8*)&u.P[wm*64+i*16+l16][ki*32+quad*8];
#pragma unroll
        for (int i=0;i<4;i++)
#pragma unroll
          for (int j=0;j<2;j++)
            o_acc[i][j] = __builtin_amdgcn_mfma_f32_16x16x32_f16(pa[i], vb[ki*2+j], o_acc[i][j], 0,0,0);
      }
      __syncthreads();
    }
  }

  // ---- epilogue: single l reduction (butterfly over l16, cross-wave via LDS) ----
#pragma unroll
  for (int d=1; d<16; d<<=1)
#pragma unroll
    for (int t=0;t<16;t++) l_lane[t] += __shfl_xor(l_lane[t], d);
  if (l16 == 0) {
#pragma unroll
    for (int i=0;i<4;i++)
#pragma unroll
      for (int r=0;r<4;r++)
        red_l[wn][wm*64+i*16+quad*4+r] = l_lane[i*4+r];
  }
  __syncthreads();

#pragma unroll
  for (int i=0;i<4;i++) {
#pragma unroll
    for (int r=0;r<4;r++) {
      int row = wm*64 + i*16 + quad*4 + r;
      float linv = 1.0f / (red_l[0][row] + red_l[1][row]);
#pragma unroll
      for (int j=0;j<2;j++) {
        int colg = h*HD_ + wn*32 + j*16 + l16;
        out[(size_t)(b*S_ + s0 + row)*D_ + colg] = o_acc[i][j][r] * linv;
      }
    }
  }
}

// ---------------- launch ----------------
extern "C" void kernel_launch(void* const* d_in, const int* in_sizes, int n_in,
                              void* d_out, int out_size, void* d_ws, size_t ws_size,
                              hipStream_t stream) {
  (void)in_sizes; (void)n_in; (void)out_size; (void)ws_size;
  const float* hs  = (const float*)d_in[0];
  const float* Wq  = (const float*)d_in[1];
  const float* Wk  = (const float*)d_in[2];
  const float* Wv  = (const float*)d_in[3];
  const float* bv  = (const float*)d_in[4];
  const float* mix = (const float*)d_in[5];
  float* out = (float*)d_out;

  char* ws = (char*)d_ws;
  f16* mix16 = (f16*)(ws);                       // 32 KB
  f16* q16   = (f16*)(ws + 32768);               // 8 MB
  f16* k16   = (f16*)(ws + 32768 + 8388608);     // 8 MB
  f16* vT    = (f16*)(ws + 32768 + 16777216);    // 8 MB

  qkv_kernel<<<dim3(D_/BN, (B_*S_)/BM, 3), 256, 0, stream>>>(
      hs, Wq, Wk, Wv, bv, mix, q16, k16, vT, mix16);
  attn_kernel<<<dim3(S_/TQ, H_, B_), 256, 0, stream>>>(
      q16, k16, vT, mix16, out);
}

// Round 9
// 468.232 us; speedup vs baseline: 1.1297x; 1.1297x over previous
//
#include <hip/hip_runtime.h>

#define B_ 2
#define S_ 2048
#define D_ 1024      // D_IN = DKQ = DV = E
#define H_ 16
#define HD_ 64       // DV / H

typedef _Float16 f16;
typedef _Float16 half8 __attribute__((ext_vector_type(8)));
typedef float float4_ __attribute__((ext_vector_type(4)));

#define N_HS (B_*S_*D_)   // 4194304
#define N_W  (D_*D_)      // 1048576
#define N_MIX (H_*D_)     // 16384

__device__ __forceinline__ void gl_lds16(const f16* g, const f16* l) {
  __builtin_amdgcn_global_load_lds(
      (const __attribute__((address_space(1))) void*)g,
      (__attribute__((address_space(3))) void*)l, 16, 0, 0);
}

// ---------------- convert fp32 -> fp16 ----------------
// mixing scaled by (1/sqrt(64)) * (1/ln2): softmax exp becomes a bare exp2
#define MIX_SCALE 0.18033688011112042f

__global__ __launch_bounds__(256) void convert_kernel(
    const float* __restrict__ hs, const float* __restrict__ wq,
    const float* __restrict__ wk, const float* __restrict__ wv,
    const float* __restrict__ mix,
    f16* __restrict__ hs16, f16* __restrict__ wq16, f16* __restrict__ wk16,
    f16* __restrict__ wv16, f16* __restrict__ mix16)
{
  const int total4 = (N_HS + 3*N_W + N_MIX) / 4;
  for (int i4 = blockIdx.x*blockDim.x + threadIdx.x; i4 < total4;
       i4 += gridDim.x*blockDim.x) {
    int i = i4*4;
    const float* src; f16* dst; float scale = 1.0f; int off;
    if (i < N_HS)            { src=hs;  dst=hs16;  off=i; }
    else if (i < N_HS+N_W)   { src=wq;  dst=wq16;  off=i-N_HS; }
    else if (i < N_HS+2*N_W) { src=wk;  dst=wk16;  off=i-N_HS-N_W; }
    else if (i < N_HS+3*N_W) { src=wv;  dst=wv16;  off=i-N_HS-2*N_W; }
    else                     { src=mix; dst=mix16; off=i-N_HS-3*N_W; scale=MIX_SCALE; }
    float4 v = *(const float4*)(src+off);
    dst[off]   = (f16)(v.x*scale);
    dst[off+1] = (f16)(v.y*scale);
    dst[off+2] = (f16)(v.z*scale);
    dst[off+3] = (f16)(v.w*scale);
  }
}

// ---------------- QKV GEMM: 128x64 tiles, DMA staging, 1536 blocks ----------------
// z==2 (V) adds bias and writes TRANSPOSED: vT[b][ch][t]
#define QBM 128
#define QBN 64
#define BK 64
#define LDA 72   // attn q-tile pad (used by attn only)

__global__ __launch_bounds__(256, 2) void qkv_kernel(
    const f16* __restrict__ hs16, const f16* __restrict__ w16base,
    const float* __restrict__ bv,
    f16* __restrict__ q16, f16* __restrict__ k16, f16* __restrict__ vT)
{
  const int z = blockIdx.z;
  const f16* W = w16base + (size_t)z * N_W;
  f16* out = (z==0) ? q16 : k16;
  const int mt = blockIdx.y, nt = blockIdx.x;
  const int tid = threadIdx.x;
  const int lane = tid & 63, wid = tid >> 6;
  const int wm = wid >> 1, wn = wid & 1;
  const int quad = lane >> 4, l16 = lane & 15;

  // unpadded, xor-swizzled chunk layout (same scheme as attn k-tiles)
  __shared__ __align__(16) f16 As[QBM*BK];   // 16 KB
  __shared__ __align__(16) f16 Bs[QBN*BK];   // 8 KB

  float4_ acc[4][2];
#pragma unroll
  for (int i=0;i<4;i++)
#pragma unroll
    for (int j=0;j<2;j++) acc[i][j] = (float4_)0.0f;

  const int row0 = mt*QBM;
  const int col0 = nt*QBN;

  for (int ko = 0; ko < D_; ko += BK) {
    // A-tile: 1024 chunks of 16B
#pragma unroll
    for (int c=0; c<4; c++) {
      int slot = (wid*4+c)*64 + lane;
      int r = slot >> 3;
      int gc = (slot & 7) ^ (r & 7);
      gl_lds16(hs16 + (size_t)(row0+r)*D_ + ko + gc*8, As + (size_t)(wid*4+c)*64*8);
    }
    // B-tile: 512 chunks
#pragma unroll
    for (int c=0; c<2; c++) {
      int slot = (wid*2+c)*64 + lane;
      int r = slot >> 3;
      int gc = (slot & 7) ^ (r & 7);
      gl_lds16(W + (size_t)(col0+r)*D_ + ko + gc*8, Bs + (size_t)(wid*2+c)*64*8);
    }
    __syncthreads();
#pragma unroll
    for (int kk=0; kk<BK; kk+=32) {
      int ck = (kk >> 3) + quad;
      half8 a[4], b[2];
#pragma unroll
      for (int i=0;i<4;i++) {
        int rr = wm*64 + i*16 + l16;
        a[i] = *(const half8*)&As[(size_t)((rr<<3) | (ck ^ (rr&7))) << 3];
      }
#pragma unroll
      for (int j=0;j<2;j++) {
        int rr = wn*32 + j*16 + l16;
        b[j] = *(const half8*)&Bs[(size_t)((rr<<3) | (ck ^ (rr&7))) << 3];
      }
#pragma unroll
      for (int i=0;i<4;i++)
#pragma unroll
        for (int j=0;j<2;j++)
          acc[i][j] = __builtin_amdgcn_mfma_f32_16x16x32_f16(a[i], b[j], acc[i][j], 0,0,0);
    }
    __syncthreads();
  }
#pragma unroll
  for (int i=0;i<4;i++) {
#pragma unroll
    for (int j=0;j<2;j++) {
      int colg = col0 + wn*32 + j*16 + l16;
      float bias = (z==2) ? bv[colg] : 0.0f;
#pragma unroll
      for (int r=0;r<4;r++) {
        int rowg = row0 + wm*64 + i*16 + quad*4 + r;
        f16 val = (f16)(acc[i][j][r] + bias);
        if (z == 2) {
          int bb = rowg >> 11, ss = rowg & (S_-1);
          vT[((size_t)bb*D_ + colg)*S_ + ss] = val;
        } else {
          out[(size_t)rowg*D_ + colg] = val;
        }
      }
    }
  }
}

// ---------------- flash attention (Round-6 version, verbatim) ----------------
// const-shift-free softmax: p = exp2(s'), s' = s/ln2 folded into mix; 2 k-tiles
// per q-stage; per-lane l partials; single epilogue reduction.
#define TQ 128
#define TK 128
#define LDP 136

__global__ __launch_bounds__(256, 2) void attn_kernel(
    const f16* __restrict__ q16, const f16* __restrict__ k16,
    const f16* __restrict__ vT, const f16* __restrict__ mix16,
    float* __restrict__ out)
{
  const int b = blockIdx.z;
  const int h = blockIdx.y;
  const int s0 = blockIdx.x * TQ;
  const int tid = threadIdx.x;
  const int lane = tid & 63, wid = tid >> 6;
  const int wm = wid >> 1, wn = wid & 1;
  const int quad = lane >> 4, l16 = lane & 15;

  // staging: q padded (VALU, mix fused) + TWO k tiles (DMA, xor-swizzled chunks)
  __shared__ __align__(16) union {
    struct { f16 q[TQ][LDA]; f16 k0[TK*BK]; f16 k1[TK*BK]; } s1;  // 51200 B
    f16 P[TQ][LDP];                                               // 34816 B
  } u;
  __shared__ __align__(16) float red_l[2][TQ];

  // per-lane l partials: 16 rows/lane (row = wm*64+i*16+quad*4+r)
  float l_lane[16];
#pragma unroll
  for (int t=0;t<16;t++) l_lane[t] = 0.0f;

  float4_ o_acc[4][2];
#pragma unroll
  for (int i=0;i<4;i++)
#pragma unroll
    for (int j=0;j<2;j++) o_acc[i][j] = (float4_)0.0f;

  const f16* qbase = q16 + (size_t)(b*S_ + s0)*D_;
  const f16* kbase = k16 + (size_t)b*S_*D_;
  const f16* mrow  = mix16 + h*D_;
  const f16* vTb   = vT + (size_t)(b*D_ + h*HD_)*S_;

  for (int t0 = 0; t0 < S_; t0 += 2*TK) {
    // ---- S[2 tiles] = (q*mix) @ k^T over K=1024 ----
    float4_ sacc[2][4][4];
#pragma unroll
    for (int tt=0;tt<2;tt++)
#pragma unroll
      for (int i=0;i<4;i++)
#pragma unroll
        for (int j=0;j<4;j++) sacc[tt][i][j] = (float4_)0.0f;

    for (int ko = 0; ko < D_; ko += BK) {
      const f16* k0g = kbase + (size_t)t0*D_ + ko;
      const f16* k1g = k0g + (size_t)TK*D_;
#pragma unroll
      for (int c=0; c<4; c++) {
        int slot = (wid*4+c)*64 + lane;
        int r = slot >> 3;
        int gc = (slot & 7) ^ (r & 7);
        gl_lds16(k0g + (size_t)r*D_ + gc*8, u.s1.k0 + (size_t)(wid*4+c)*64*8);
        gl_lds16(k1g + (size_t)r*D_ + gc*8, u.s1.k1 + (size_t)(wid*4+c)*64*8);
      }
      // q-tile: VALU staging with mix fused, padded layout (once per 2 k-tiles)
#pragma unroll
      for (int it=0; it<4; it++) {
        int c = it*256 + tid;
        int r = c >> 3, c8 = (c & 7)*8;
        half8 qv = *(const half8*)&qbase[(size_t)r*D_ + ko + c8];
        half8 mv = *(const half8*)&mrow[ko + c8];
        *(half8*)&u.s1.q[r][c8] = qv * mv;
      }
      __syncthreads();
#pragma unroll
      for (int kk=0; kk<BK; kk+=32) {
        half8 a[4];
#pragma unroll
        for (int i=0;i<4;i++) a[i] = *(const half8*)&u.s1.q[wm*64+i*16+l16][kk+quad*8];
#pragma unroll
        for (int tt=0;tt<2;tt++) {
          const f16* kb = tt ? u.s1.k1 : u.s1.k0;
          half8 bf[4];
#pragma unroll
          for (int j=0;j<4;j++) {
            int rr = wn*64 + j*16 + l16;
            int ck = (kk >> 3) + quad;
            bf[j] = *(const half8*)&kb[(size_t)(((rr<<3) | (ck ^ (rr&7))) << 3)];
          }
#pragma unroll
          for (int i=0;i<4;i++)
#pragma unroll
            for (int j=0;j<4;j++)
              sacc[tt][i][j] = __builtin_amdgcn_mfma_f32_16x16x32_f16(a[i], bf[j], sacc[tt][i][j], 0,0,0);
        }
      }
      __syncthreads();
    }

    // ---- per sub-tile: P = exp2(S), l partials, P->LDS, PV ----
#pragma unroll
    for (int tt=0;tt<2;tt++) {
#pragma unroll
      for (int i=0;i<4;i++)
#pragma unroll
        for (int j=0;j<4;j++)
#pragma unroll
          for (int r=0;r<4;r++) {
            float p = __builtin_exp2f(sacc[tt][i][j][r]);
            l_lane[i*4+r] += p;
            u.P[wm*64+i*16+quad*4+r][wn*64+j*16+l16] = (f16)p;
          }

      // prefetch PV B-fragments (latency hides under barrier)
      half8 vb[8];
#pragma unroll
      for (int ki=0; ki<4; ki++)
#pragma unroll
        for (int j=0; j<2; j++) {
          int ch = wn*32 + j*16 + l16;
          vb[ki*2+j] = *(const half8*)&vTb[(size_t)ch*S_ + t0 + tt*TK + ki*32 + quad*8];
        }

      __syncthreads();

#pragma unroll
      for (int ki=0; ki<4; ki++) {
        half8 pa[4];
#pragma unroll
        for (int i=0;i<4;i++) pa[i] = *(const half8*)&u.P[wm*64+i*16+l16][ki*32+quad*8];
#pragma unroll
        for (int i=0;i<4;i++)
#pragma unroll
          for (int j=0;j<2;j++)
            o_acc[i][j] = __builtin_amdgcn_mfma_f32_16x16x32_f16(pa[i], vb[ki*2+j], o_acc[i][j], 0,0,0);
      }
      __syncthreads();
    }
  }

  // ---- epilogue: single l reduction (butterfly over l16, cross-wave via LDS) ----
#pragma unroll
  for (int d=1; d<16; d<<=1)
#pragma unroll
    for (int t=0;t<16;t++) l_lane[t] += __shfl_xor(l_lane[t], d);
  if (l16 == 0) {
#pragma unroll
    for (int i=0;i<4;i++)
#pragma unroll
      for (int r=0;r<4;r++)
        red_l[wn][wm*64+i*16+quad*4+r] = l_lane[i*4+r];
  }
  __syncthreads();

#pragma unroll
  for (int i=0;i<4;i++) {
#pragma unroll
    for (int r=0;r<4;r++) {
      int row = wm*64 + i*16 + quad*4 + r;
      float linv = 1.0f / (red_l[0][row] + red_l[1][row]);
#pragma unroll
      for (int j=0;j<2;j++) {
        int colg = h*HD_ + wn*32 + j*16 + l16;
        out[(size_t)(b*S_ + s0 + row)*D_ + colg] = o_acc[i][j][r] * linv;
      }
    }
  }
}

// ---------------- launch ----------------
extern "C" void kernel_launch(void* const* d_in, const int* in_sizes, int n_in,
                              void* d_out, int out_size, void* d_ws, size_t ws_size,
                              hipStream_t stream) {
  (void)in_sizes; (void)n_in; (void)out_size; (void)ws_size;
  const float* hs  = (const float*)d_in[0];
  const float* Wq  = (const float*)d_in[1];
  const float* Wk  = (const float*)d_in[2];
  const float* Wv  = (const float*)d_in[3];
  const float* bv  = (const float*)d_in[4];
  const float* mix = (const float*)d_in[5];
  float* out = (float*)d_out;

  char* ws = (char*)d_ws;
  f16* hs16  = (f16*)(ws);                       // 8 MB
  f16* w16   = (f16*)(ws + 8388608);             // 6 MB
  f16* mix16 = (f16*)(ws + 14680064);            // 32 KB
  f16* q16   = (f16*)(ws + 14712832);            // 8 MB
  f16* k16   = (f16*)(ws + 23101440);            // 8 MB
  f16* vT    = (f16*)(ws + 31490048);            // 8 MB

  convert_kernel<<<2048, 256, 0, stream>>>(hs, Wq, Wk, Wv, mix,
                                           hs16, w16, w16+N_W, w16+2*N_W, mix16);
  qkv_kernel<<<dim3(D_/QBN, (B_*S_)/QBM, 3), 256, 0, stream>>>(
      hs16, w16, bv, q16, k16, vT);
  attn_kernel<<<dim3(S_/TQ, H_, B_), 256, 0, stream>>>(
      q16, k16, vT, mix16, out);
}

// Round 10
// 431.801 us; speedup vs baseline: 1.2250x; 1.0844x over previous
//
#include <hip/hip_runtime.h>

#define B_ 2
#define S_ 2048
#define D_ 1024      // D_IN = DKQ = DV = E
#define H_ 16
#define HD_ 64       // DV / H

typedef _Float16 f16;
typedef _Float16 half8 __attribute__((ext_vector_type(8)));
typedef float float4_ __attribute__((ext_vector_type(4)));

#define N_HS (B_*S_*D_)   // 4194304
#define N_W  (D_*D_)      // 1048576
#define N_MIX (H_*D_)     // 16384

__device__ __forceinline__ void gl_lds16(const f16* g, const f16* l) {
  __builtin_amdgcn_global_load_lds(
      (const __attribute__((address_space(1))) void*)g,
      (__attribute__((address_space(3))) void*)l, 16, 0, 0);
}

// ---------------- convert fp32 -> fp16 ----------------
// mixing scaled by (1/sqrt(64)) * (1/ln2): softmax exp becomes a bare exp2
#define MIX_SCALE 0.18033688011112042f

__global__ __launch_bounds__(256) void convert_kernel(
    const float* __restrict__ hs, const float* __restrict__ wq,
    const float* __restrict__ wk, const float* __restrict__ wv,
    const float* __restrict__ mix,
    f16* __restrict__ hs16, f16* __restrict__ wq16, f16* __restrict__ wk16,
    f16* __restrict__ wv16, f16* __restrict__ mix16)
{
  const int total4 = (N_HS + 3*N_W + N_MIX) / 4;
  for (int i4 = blockIdx.x*blockDim.x + threadIdx.x; i4 < total4;
       i4 += gridDim.x*blockDim.x) {
    int i = i4*4;
    const float* src; f16* dst; float scale = 1.0f; int off;
    if (i < N_HS)            { src=hs;  dst=hs16;  off=i; }
    else if (i < N_HS+N_W)   { src=wq;  dst=wq16;  off=i-N_HS; }
    else if (i < N_HS+2*N_W) { src=wk;  dst=wk16;  off=i-N_HS-N_W; }
    else if (i < N_HS+3*N_W) { src=wv;  dst=wv16;  off=i-N_HS-2*N_W; }
    else                     { src=mix; dst=mix16; off=i-N_HS-3*N_W; scale=MIX_SCALE; }
    float4 v = *(const float4*)(src+off);
    dst[off]   = (f16)(v.x*scale);
    dst[off+1] = (f16)(v.y*scale);
    dst[off+2] = (f16)(v.z*scale);
    dst[off+3] = (f16)(v.w*scale);
  }
}

// ---------------- QKV GEMM: 128x128 tiles, DMA staging (m97-style) ----------------
// z==2 (V) adds bias and writes TRANSPOSED: vT[b][ch][t]
#define BM 128
#define BN 128
#define BK 64
#define LDA 72   // attn q-tile pad (used by attn only)

__global__ __launch_bounds__(256, 2) void qkv_kernel(
    const f16* __restrict__ hs16, const f16* __restrict__ w16base,
    const float* __restrict__ bv,
    f16* __restrict__ q16, f16* __restrict__ k16, f16* __restrict__ vT)
{
  const int z = blockIdx.z;
  const f16* W = w16base + (size_t)z * N_W;
  f16* out = (z==0) ? q16 : k16;
  const int mt = blockIdx.y, nt = blockIdx.x;
  const int tid = threadIdx.x;
  const int lane = tid & 63, wid = tid >> 6;
  const int wm = wid >> 1, wn = wid & 1;
  const int quad = lane >> 4, l16 = lane & 15;

  // unpadded, xor-swizzled chunk layout (same scheme as attn k-tiles)
  __shared__ __align__(16) f16 As[BM*BK];   // 16 KB
  __shared__ __align__(16) f16 Bs[BN*BK];   // 16 KB

  float4_ acc[4][4];
#pragma unroll
  for (int i=0;i<4;i++)
#pragma unroll
    for (int j=0;j<4;j++) acc[i][j] = (float4_)0.0f;

  const int row0 = mt*BM;
  const int col0 = nt*BN;

  for (int ko = 0; ko < D_; ko += BK) {
#pragma unroll
    for (int c=0; c<4; c++) {
      int slot = (wid*4+c)*64 + lane;      // 0..1023 16B chunks
      int r = slot >> 3;
      int gc = (slot & 7) ^ (r & 7);
      gl_lds16(hs16 + (size_t)(row0+r)*D_ + ko + gc*8, As + (size_t)(wid*4+c)*64*8);
      gl_lds16(W    + (size_t)(col0+r)*D_ + ko + gc*8, Bs + (size_t)(wid*4+c)*64*8);
    }
    __syncthreads();
#pragma unroll
    for (int kk=0; kk<BK; kk+=32) {
      int ck = (kk >> 3) + quad;
      half8 a[4], b[4];
#pragma unroll
      for (int i=0;i<4;i++) {
        int rr = wm*64 + i*16 + l16;
        a[i] = *(const half8*)&As[(size_t)(((rr<<3) | (ck ^ (rr&7))) << 3)];
      }
#pragma unroll
      for (int j=0;j<4;j++) {
        int rr = wn*64 + j*16 + l16;
        b[j] = *(const half8*)&Bs[(size_t)(((rr<<3) | (ck ^ (rr&7))) << 3)];
      }
#pragma unroll
      for (int i=0;i<4;i++)
#pragma unroll
        for (int j=0;j<4;j++)
          acc[i][j] = __builtin_amdgcn_mfma_f32_16x16x32_f16(a[i], b[j], acc[i][j], 0,0,0);
    }
    __syncthreads();
  }
#pragma unroll
  for (int i=0;i<4;i++) {
#pragma unroll
    for (int j=0;j<4;j++) {
      int colg = col0 + wn*64 + j*16 + l16;
      float bias = (z==2) ? bv[colg] : 0.0f;
#pragma unroll
      for (int r=0;r<4;r++) {
        int rowg = row0 + wm*64 + i*16 + quad*4 + r;
        f16 val = (f16)(acc[i][j][r] + bias);
        if (z == 2) {
          int bb = rowg >> 11, ss = rowg & (S_-1);
          vT[((size_t)bb*D_ + colg)*S_ + ss] = val;
        } else {
          out[(size_t)rowg*D_ + colg] = val;
        }
      }
    }
  }
}

// ---------------- flash attention (Round-6 version, verbatim) ----------------
// const-shift-free softmax: p = exp2(s'), s' = s/ln2 folded into mix; 2 k-tiles
// per q-stage; per-lane l partials; single epilogue reduction.
#define TQ 128
#define TK 128
#define LDP 136

__global__ __launch_bounds__(256, 2) void attn_kernel(
    const f16* __restrict__ q16, const f16* __restrict__ k16,
    const f16* __restrict__ vT, const f16* __restrict__ mix16,
    float* __restrict__ out)
{
  const int b = blockIdx.z;
  const int h = blockIdx.y;
  const int s0 = blockIdx.x * TQ;
  const int tid = threadIdx.x;
  const int lane = tid & 63, wid = tid >> 6;
  const int wm = wid >> 1, wn = wid & 1;
  const int quad = lane >> 4, l16 = lane & 15;

  // staging: q padded (VALU, mix fused) + TWO k tiles (DMA, xor-swizzled chunks)
  __shared__ __align__(16) union {
    struct { f16 q[TQ][LDA]; f16 k0[TK*BK]; f16 k1[TK*BK]; } s1;  // 51200 B
    f16 P[TQ][LDP];                                               // 34816 B
  } u;
  __shared__ __align__(16) float red_l[2][TQ];

  // per-lane l partials: 16 rows/lane (row = wm*64+i*16+quad*4+r)
  float l_lane[16];
#pragma unroll
  for (int t=0;t<16;t++) l_lane[t] = 0.0f;

  float4_ o_acc[4][2];
#pragma unroll
  for (int i=0;i<4;i++)
#pragma unroll
    for (int j=0;j<2;j++) o_acc[i][j] = (float4_)0.0f;

  const f16* qbase = q16 + (size_t)(b*S_ + s0)*D_;
  const f16* kbase = k16 + (size_t)b*S_*D_;
  const f16* mrow  = mix16 + h*D_;
  const f16* vTb   = vT + (size_t)(b*D_ + h*HD_)*S_;

  for (int t0 = 0; t0 < S_; t0 += 2*TK) {
    // ---- S[2 tiles] = (q*mix) @ k^T over K=1024 ----
    float4_ sacc[2][4][4];
#pragma unroll
    for (int tt=0;tt<2;tt++)
#pragma unroll
      for (int i=0;i<4;i++)
#pragma unroll
        for (int j=0;j<4;j++) sacc[tt][i][j] = (float4_)0.0f;

    for (int ko = 0; ko < D_; ko += BK) {
      const f16* k0g = kbase + (size_t)t0*D_ + ko;
      const f16* k1g = k0g + (size_t)TK*D_;
#pragma unroll
      for (int c=0; c<4; c++) {
        int slot = (wid*4+c)*64 + lane;
        int r = slot >> 3;
        int gc = (slot & 7) ^ (r & 7);
        gl_lds16(k0g + (size_t)r*D_ + gc*8, u.s1.k0 + (size_t)(wid*4+c)*64*8);
        gl_lds16(k1g + (size_t)r*D_ + gc*8, u.s1.k1 + (size_t)(wid*4+c)*64*8);
      }
      // q-tile: VALU staging with mix fused, padded layout (once per 2 k-tiles)
#pragma unroll
      for (int it=0; it<4; it++) {
        int c = it*256 + tid;
        int r = c >> 3, c8 = (c & 7)*8;
        half8 qv = *(const half8*)&qbase[(size_t)r*D_ + ko + c8];
        half8 mv = *(const half8*)&mrow[ko + c8];
        *(half8*)&u.s1.q[r][c8] = qv * mv;
      }
      __syncthreads();
#pragma unroll
      for (int kk=0; kk<BK; kk+=32) {
        half8 a[4];
#pragma unroll
        for (int i=0;i<4;i++) a[i] = *(const half8*)&u.s1.q[wm*64+i*16+l16][kk+quad*8];
#pragma unroll
        for (int tt=0;tt<2;tt++) {
          const f16* kb = tt ? u.s1.k1 : u.s1.k0;
          half8 bf[4];
#pragma unroll
          for (int j=0;j<4;j++) {
            int rr = wn*64 + j*16 + l16;
            int ck = (kk >> 3) + quad;
            bf[j] = *(const half8*)&kb[(size_t)(((rr<<3) | (ck ^ (rr&7))) << 3)];
          }
#pragma unroll
          for (int i=0;i<4;i++)
#pragma unroll
            for (int j=0;j<4;j++)
              sacc[tt][i][j] = __builtin_amdgcn_mfma_f32_16x16x32_f16(a[i], bf[j], sacc[tt][i][j], 0,0,0);
        }
      }
      __syncthreads();
    }

    // ---- per sub-tile: P = exp2(S), l partials, P->LDS, PV ----
#pragma unroll
    for (int tt=0;tt<2;tt++) {
#pragma unroll
      for (int i=0;i<4;i++)
#pragma unroll
        for (int j=0;j<4;j++)
#pragma unroll
          for (int r=0;r<4;r++) {
            float p = __builtin_exp2f(sacc[tt][i][j][r]);
            l_lane[i*4+r] += p;
            u.P[wm*64+i*16+quad*4+r][wn*64+j*16+l16] = (f16)p;
          }

      // prefetch PV B-fragments (latency hides under barrier)
      half8 vb[8];
#pragma unroll
      for (int ki=0; ki<4; ki++)
#pragma unroll
        for (int j=0; j<2; j++) {
          int ch = wn*32 + j*16 + l16;
          vb[ki*2+j] = *(const half8*)&vTb[(size_t)ch*S_ + t0 + tt*TK + ki*32 + quad*8];
        }

      __syncthreads();

#pragma unroll
      for (int ki=0; ki<4; ki++) {
        half8 pa[4];
#pragma unroll
        for (int i=0;i<4;i++) pa[i] = *(const half8*)&u.P[wm*64+i*16+l16][ki*32+quad*8];
#pragma unroll
        for (int i=0;i<4;i++)
#pragma unroll
          for (int j=0;j<2;j++)
            o_acc[i][j] = __builtin_amdgcn_mfma_f32_16x16x32_f16(pa[i], vb[ki*2+j], o_acc[i][j], 0,0,0);
      }
      __syncthreads();
    }
  }

  // ---- epilogue: single l reduction (butterfly over l16, cross-wave via LDS) ----
#pragma unroll
  for (int d=1; d<16; d<<=1)
#pragma unroll
    for (int t=0;t<16;t++) l_lane[t] += __shfl_xor(l_lane[t], d);
  if (l16 == 0) {
#pragma unroll
    for (int i=0;i<4;i++)
#pragma unroll
      for (int r=0;r<4;r++)
        red_l[wn][wm*64+i*16+quad*4+r] = l_lane[i*4+r];
  }
  __syncthreads();

#pragma unroll
  for (int i=0;i<4;i++) {
#pragma unroll
    for (int r=0;r<4;r++) {
      int row = wm*64 + i*16 + quad*4 + r;
      float linv = 1.0f / (red_l[0][row] + red_l[1][row]);
#pragma unroll
      for (int j=0;j<2;j++) {
        int colg = h*HD_ + wn*32 + j*16 + l16;
        out[(size_t)(b*S_ + s0 + row)*D_ + colg] = o_acc[i][j][r] * linv;
      }
    }
  }
}

// ---------------- launch ----------------
extern "C" void kernel_launch(void* const* d_in, const int* in_sizes, int n_in,
                              void* d_out, int out_size, void* d_ws, size_t ws_size,
                              hipStream_t stream) {
  (void)in_sizes; (void)n_in; (void)out_size; (void)ws_size;
  const float* hs  = (const float*)d_in[0];
  const float* Wq  = (const float*)d_in[1];
  const float* Wk  = (const float*)d_in[2];
  const float* Wv  = (const float*)d_in[3];
  const float* bv  = (const float*)d_in[4];
  const float* mix = (const float*)d_in[5];
  float* out = (float*)d_out;

  char* ws = (char*)d_ws;
  f16* hs16  = (f16*)(ws);                       // 8 MB
  f16* w16   = (f16*)(ws + 8388608);             // 6 MB
  f16* mix16 = (f16*)(ws + 14680064);            // 32 KB
  f16* q16   = (f16*)(ws + 14712832);            // 8 MB
  f16* k16   = (f16*)(ws + 23101440);            // 8 MB
  f16* vT    = (f16*)(ws + 31490048);            // 8 MB

  convert_kernel<<<2048, 256, 0, stream>>>(hs, Wq, Wk, Wv, mix,
                                           hs16, w16, w16+N_W, w16+2*N_W, mix16);
  qkv_kernel<<<dim3(D_/BN, (B_*S_)/BM, 3), 256, 0, stream>>>(
      hs16, w16, bv, q16, k16, vT);
  attn_kernel<<<dim3(S_/TQ, H_, B_), 256, 0, stream>>>(
      q16, k16, vT, mix16, out);
}